// Round 1
// baseline (847.853 us; speedup 1.0000x reference)
//
#include <hip/hip_runtime.h>

#define CD 768
#define NHEAD 12
#define DH 64
#define BSZ 2
#define NM_ 4096
#define NX_ 16384
#define EPSF 1e-6f

using bf16x8 = __attribute__((ext_vector_type(8))) short;
using f32x4  = __attribute__((ext_vector_type(4))) float;

__device__ inline unsigned short bf16r(float f) {
  union { float f; unsigned u; } un; un.f = f;
  unsigned u = un.u;
  u += 0x7fffu + ((u >> 16) & 1u);
  return (unsigned short)(u >> 16);
}

// ---------------- convert f32 -> bf16 (vectorized x4) ----------------
__global__ __launch_bounds__(256) void cvt_bf16(const float* __restrict__ in,
                                                unsigned short* __restrict__ out, int n4) {
  int i = blockIdx.x * 256 + threadIdx.x;
  if (i >= n4) return;
  float4 v = ((const float4*)in)[i];
  ushort4 o;
  o.x = bf16r(v.x); o.y = bf16r(v.y); o.z = bf16r(v.z); o.w = bf16r(v.w);
  ((ushort4*)out)[i] = o;
}

// ---------------- softplus(scale) -> sp[768] ----------------
__global__ void softplus_k(const float* __restrict__ s, float* __restrict__ sp) {
  int i = blockIdx.x * 256 + threadIdx.x;
  if (i < CD) sp[i] = log1pf(expf(s[i]));
}

// ---------------- C[M,N] = A[M,K] @ B[N,K]^T (+bias), bf16 in, f32 out -----
// 64x64 tile / 256 threads (4 waves); wave w owns rows [w*16, w*16+16).
__global__ __launch_bounds__(256) void gemm_bt(const unsigned short* __restrict__ A,
                                               const unsigned short* __restrict__ Bm,
                                               float* __restrict__ Cm,
                                               const float* __restrict__ bias,
                                               int M, int N, int K) {
  __shared__ __align__(16) unsigned short As[64][48];  // stride 48 keeps 16B align
  __shared__ __align__(16) unsigned short Bs[64][48];
  const int m0 = blockIdx.x * 64, n0 = blockIdx.y * 64;
  const int tid = threadIdx.x;
  const int wave = tid >> 6, lane = tid & 63;
  const int quad = lane >> 4, l16 = lane & 15;
  const int sr = tid >> 2, sc = (tid & 3) * 8;   // staging: 8 bf16 (16B) per thread
  f32x4 acc0 = {0.f,0.f,0.f,0.f}, acc1 = {0.f,0.f,0.f,0.f};
  f32x4 acc2 = {0.f,0.f,0.f,0.f}, acc3 = {0.f,0.f,0.f,0.f};
  for (int k0 = 0; k0 < K; k0 += 32) {
    int4 av = *(const int4*)(A + (size_t)(m0 + sr) * K + (k0 + sc));
    int4 bv = *(const int4*)(Bm + (size_t)(n0 + sr) * K + (k0 + sc));
    __syncthreads();
    *(int4*)(&As[sr][sc]) = av;
    *(int4*)(&Bs[sr][sc]) = bv;
    __syncthreads();
    bf16x8 af = *(const bf16x8*)(&As[wave * 16 + l16][quad * 8]);
    bf16x8 b0 = *(const bf16x8*)(&Bs[ 0 + l16][quad * 8]);
    bf16x8 b1 = *(const bf16x8*)(&Bs[16 + l16][quad * 8]);
    bf16x8 b2 = *(const bf16x8*)(&Bs[32 + l16][quad * 8]);
    bf16x8 b3 = *(const bf16x8*)(&Bs[48 + l16][quad * 8]);
    acc0 = __builtin_amdgcn_mfma_f32_16x16x32_bf16(af, b0, acc0, 0, 0, 0);
    acc1 = __builtin_amdgcn_mfma_f32_16x16x32_bf16(af, b1, acc1, 0, 0, 0);
    acc2 = __builtin_amdgcn_mfma_f32_16x16x32_bf16(af, b2, acc2, 0, 0, 0);
    acc3 = __builtin_amdgcn_mfma_f32_16x16x32_bf16(af, b3, acc3, 0, 0, 0);
  }
  // epilogue: D[row][col], col = lane&15, row = quad*4 + reg  [m89/m91 verified]
  const int rbase = m0 + wave * 16 + quad * 4;
  f32x4 accs[4] = {acc0, acc1, acc2, acc3};
  for (int cg = 0; cg < 4; ++cg) {
    const int cc = n0 + cg * 16 + l16;
    float bv = bias ? bias[cc] : 0.f;
    for (int r = 0; r < 4; ++r) {
      Cm[(size_t)(rbase + r) * N + cc] = accs[cg][r] + bv;
    }
  }
}

// ---------------- _process: in-place over rows of 768, norm over full C ----
__global__ __launch_bounds__(256) void process_rows(float* __restrict__ X,
                                                    const float* __restrict__ sp) {
  const int row = blockIdx.x;
  const int tid = threadIdx.x;
  float* xr = X + (size_t)row * CD;
  float tv[3];
  float n2 = 0.f, m2 = 0.f;
  #pragma unroll
  for (int i = 0; i < 3; ++i) {
    int c = tid + i * 256;
    float t = fmaxf(xr[c], 0.f) + EPSF;
    t = t / sp[c];
    tv[i] = t;
    float t2 = t * t;
    n2 += t2;
    float p = t2 * t;
    m2 += p * p;
  }
  #pragma unroll
  for (int off = 32; off; off >>= 1) {
    n2 += __shfl_down(n2, off, 64);
    m2 += __shfl_down(m2, off, 64);
  }
  __shared__ float rn[4], rm[4];
  if ((tid & 63) == 0) { rn[tid >> 6] = n2; rm[tid >> 6] = m2; }
  __syncthreads();
  float N2 = rn[0] + rn[1] + rn[2] + rn[3];
  float M2 = rm[0] + rm[1] + rm[2] + rm[3];
  float factor = sqrtf(N2 / M2);   // = ||t|| / ||t^3||
  #pragma unroll
  for (int i = 0; i < 3; ++i) {
    int c = tid + i * 256;
    float t = tv[i];
    xr[c] = t * t * t * factor;
  }
}

// ---------------- k_mean[b,c] = (1/Nm) sum_n k[(n*B+b)*C + c] ----------------
__global__ __launch_bounds__(256) void kmean_k(const float* __restrict__ Kp,
                                               float* __restrict__ km) {
  int blk = blockIdx.x;            // B * 3 * 16 = 96 blocks
  int b = blk / 48;
  int r = blk % 48;
  int cch = r / 16, nch = r % 16;
  int c = cch * 256 + threadIdx.x;
  float s = 0.f;
  for (int i = 0; i < 256; ++i) {
    int n = nch * 256 + i;
    s += Kp[((size_t)n * BSZ + b) * CD + c];
  }
  atomicAdd(&km[b * CD + c], s * (1.f / NM_));
}

// ---------------- kv[bh,d,e] = (1/Nm) sum_n k[n,d]*v[n,e] (split-K atomic) ---
__global__ __launch_bounds__(256) void kv_k(const float* __restrict__ Kp,
                                            const float* __restrict__ Vp,
                                            float* __restrict__ kv) {
  const int bh = blockIdx.x;
  const int b = bh / NHEAD, hh = bh % NHEAD;
  const int nch = blockIdx.y;          // 16 chunks of 256 tokens
  __shared__ float ks[64][68];
  __shared__ float vs[64][68];
  const int tid = threadIdx.x;
  const int d = tid & 63, eg = tid >> 6;
  const int rn = tid >> 2, cb = (tid & 3) * 16;
  float acc[16];
  #pragma unroll
  for (int j = 0; j < 16; ++j) acc[j] = 0.f;
  for (int sub = 0; sub < 4; ++sub) {
    int n0 = nch * 256 + sub * 64;
    __syncthreads();
    const float* kg = Kp + ((size_t)(n0 + rn) * BSZ + b) * CD + hh * 64 + cb;
    const float* vg = Vp + ((size_t)(n0 + rn) * BSZ + b) * CD + hh * 64 + cb;
    #pragma unroll
    for (int i = 0; i < 4; ++i) {
      *(float4*)(&ks[rn][cb + i * 4]) = *(const float4*)(kg + i * 4);
      *(float4*)(&vs[rn][cb + i * 4]) = *(const float4*)(vg + i * 4);
    }
    __syncthreads();
    for (int n = 0; n < 64; ++n) {
      float a = ks[n][d];
      const float* vr = &vs[n][eg * 16];
      #pragma unroll
      for (int j = 0; j < 16; ++j) acc[j] += a * vr[j];
    }
  }
  float* outp = kv + (size_t)bh * 4096 + d * 64 + eg * 16;
  #pragma unroll
  for (int j = 0; j < 16; ++j) atomicAdd(&outp[j], acc[j] * (1.f / NM_));
}

// ---------------- depthwise 5x5 conv over (H=16, W*T=256) grid ----------------
__global__ __launch_bounds__(256) void dwconv_k(const float* __restrict__ Vp,
                                                const float* __restrict__ w,
                                                const float* __restrict__ bias,
                                                float* __restrict__ outp) {
  __shared__ float wsm[64 * 25];
  __shared__ float bsm[64];
  for (int i = threadIdx.x; i < 1600; i += 256) wsm[i] = w[i];
  if (threadIdx.x < 64) bsm[threadIdx.x] = bias[threadIdx.x];
  __syncthreads();
  int idx = blockIdx.x * 256 + threadIdx.x;     // total NM_*BSZ*CD
  if (idx >= NM_ * BSZ * CD) return;
  int c = idx % CD;
  int b = (idx / CD) % BSZ;
  int m = idx / (CD * BSZ);
  int dd = c & 63;
  int y = m >> 8, x = m & 255;
  float s = bsm[dd];
  #pragma unroll
  for (int dy = 0; dy < 5; ++dy) {
    int yy = y + dy - 2;
    if (yy < 0 || yy >= 16) continue;
    #pragma unroll
    for (int dx = 0; dx < 5; ++dx) {
      int xx = x + dx - 2;
      if (xx < 0 || xx >= 256) continue;
      s += wsm[dd * 25 + dy * 5 + dx] *
           Vp[((size_t)((yy << 8) + xx) * BSZ + b) * CD + c];
    }
  }
  outp[idx] = s;   // layout (m*B + b)*C + c
}

// -------- attn out: tmp[b,n,c] = bf16( z * (q . kv)[e] + dwc[b, n%Nm, c] ) ----
__global__ __launch_bounds__(256) void attn_out_k(const float* __restrict__ Q,
                                                  const float* __restrict__ kv,
                                                  const float* __restrict__ km,
                                                  const float* __restrict__ dwc,
                                                  unsigned short* __restrict__ tmpb) {
  const int bh = blockIdx.x, b = bh / NHEAD, hh = bh % NHEAD;
  const int n0 = blockIdx.y * 64;
  __shared__ float kvs[64][68];
  __shared__ float qs[64][68];
  __shared__ float kms[64];
  const int tid = threadIdx.x;
  {
    int rn = tid >> 2, cb = (tid & 3) * 16;
    const float* src = kv + (size_t)bh * 4096 + rn * 64 + cb;
    const float* qsrc = Q + ((size_t)(n0 + rn) * BSZ + b) * CD + hh * 64 + cb;
    #pragma unroll
    for (int i = 0; i < 4; ++i) {
      *(float4*)(&kvs[rn][cb + i * 4]) = *(const float4*)(src + i * 4);
      *(float4*)(&qs[rn][cb + i * 4]) = *(const float4*)(qsrc + i * 4);
    }
    if (tid < 64) kms[tid] = km[b * CD + hh * 64 + tid];
  }
  __syncthreads();
  const int i = tid >> 2, eg = tid & 3;
  float zs = 0.f;
  #pragma unroll
  for (int d = 0; d < 64; ++d) zs += qs[i][d] * kms[d];
  float z = 1.f / (zs + EPSF);
  float acc[16];
  #pragma unroll
  for (int j = 0; j < 16; ++j) acc[j] = 0.f;
  for (int d = 0; d < 64; ++d) {
    float qd = qs[i][d];
    const float* kr = &kvs[d][eg * 16];
    #pragma unroll
    for (int j = 0; j < 16; ++j) acc[j] += qd * kr[j];
  }
  const int n = n0 + i;
  const int m = n & (NM_ - 1);
  const int cbase = hh * 64 + eg * 16;
  const float* dsrc = dwc + ((size_t)m * BSZ + b) * CD + cbase;
  unsigned short* dst = tmpb + ((size_t)n * BSZ + b) * CD + cbase;
  #pragma unroll
  for (int j = 0; j < 16; ++j) dst[j] = bf16r(acc[j] * z + dsrc[j]);
}

// =============================== launcher ===============================
extern "C" void kernel_launch(void* const* d_in, const int* in_sizes, int n_in,
                              void* d_out, int out_size, void* d_ws, size_t ws_size,
                              hipStream_t stream) {
  const float* x      = (const float*)d_in[0];
  const float* memory = (const float*)d_in[1];
  const float* w_q    = (const float*)d_in[2];
  const float* w_k    = (const float*)d_in[3];
  const float* w_v    = (const float*)d_in[4];
  const float* w_proj = (const float*)d_in[5];
  const float* b_proj = (const float*)d_in[6];
  const float* dwc_w  = (const float*)d_in[7];
  const float* dwc_b  = (const float*)d_in[8];
  const float* scale  = (const float*)d_in[9];
  float* out = (float*)d_out;

  const int Mq = NX_ * BSZ;   // 32768
  const int Mm = NM_ * BSZ;   // 8192

  char* ws = (char*)d_ws;
  size_t off = 0;
  auto alloc = [&](size_t bytes) -> void* {
    void* p = ws + off;
    off += (bytes + 255) & ~(size_t)255;
    return p;
  };
  float* q    = (float*)alloc((size_t)Mq * CD * 4);   // 100.7 MB
  float* kbuf = (float*)alloc((size_t)Mm * CD * 4);   // 25.2 MB (reused as dwcbuf)
  float* vbuf = (float*)alloc((size_t)Mm * CD * 4);   // 25.2 MB
  float* kv   = (float*)alloc((size_t)BSZ * NHEAD * DH * DH * 4);
  float* km   = (float*)alloc((size_t)BSZ * CD * 4);
  float* sp   = (float*)alloc(CD * 4);
  unsigned short* xb  = (unsigned short*)alloc((size_t)Mq * CD * 2);  // reused as tmpb
  unsigned short* mb  = (unsigned short*)alloc((size_t)Mm * CD * 2);
  unsigned short* wqb = (unsigned short*)alloc((size_t)CD * CD * 2);
  unsigned short* wkb = (unsigned short*)alloc((size_t)CD * CD * 2);
  unsigned short* wvb = (unsigned short*)alloc((size_t)CD * CD * 2);
  unsigned short* wpb = (unsigned short*)alloc((size_t)CD * CD * 2);

  hipMemsetAsync(kv, 0, (size_t)BSZ * NHEAD * DH * DH * 4, stream);
  hipMemsetAsync(km, 0, (size_t)BSZ * CD * 4, stream);

  softplus_k<<<3, 256, 0, stream>>>(scale, sp);

  auto cvt = [&](const float* src, unsigned short* dst, size_t n) {
    int n4 = (int)(n / 4);
    cvt_bf16<<<(n4 + 255) / 256, 256, 0, stream>>>(src, dst, n4);
  };
  cvt(x,      xb,  (size_t)Mq * CD);
  cvt(memory, mb,  (size_t)Mm * CD);
  cvt(w_q,    wqb, (size_t)CD * CD);
  cvt(w_k,    wkb, (size_t)CD * CD);
  cvt(w_v,    wvb, (size_t)CD * CD);
  cvt(w_proj, wpb, (size_t)CD * CD);

  gemm_bt<<<dim3(Mq / 64, CD / 64), 256, 0, stream>>>(xb, wqb, q,    nullptr, Mq, CD, CD);
  gemm_bt<<<dim3(Mm / 64, CD / 64), 256, 0, stream>>>(mb, wkb, kbuf, nullptr, Mm, CD, CD);
  gemm_bt<<<dim3(Mm / 64, CD / 64), 256, 0, stream>>>(mb, wvb, vbuf, nullptr, Mm, CD, CD);

  process_rows<<<Mq, 256, 0, stream>>>(q, sp);
  process_rows<<<Mm, 256, 0, stream>>>(kbuf, sp);

  kmean_k<<<96, 256, 0, stream>>>(kbuf, km);
  kv_k<<<dim3(BSZ * NHEAD, 16), 256, 0, stream>>>(kbuf, vbuf, kv);

  float* dwcbuf = kbuf;  // k fully consumed; reuse
  dwconv_k<<<(NM_ * BSZ * CD) / 256, 256, 0, stream>>>(vbuf, dwc_w, dwc_b, dwcbuf);

  unsigned short* tmpb = xb;  // xb fully consumed; reuse
  attn_out_k<<<dim3(BSZ * NHEAD, NX_ / 64), 256, 0, stream>>>(q, kv, km, dwcbuf, tmpb);

  gemm_bt<<<dim3(Mq / 64, CD / 64), 256, 0, stream>>>(tmpb, wpb, out, b_proj, Mq, CD, CD);
}

// Round 2
// 687.097 us; speedup vs baseline: 1.2340x; 1.2340x over previous
//
#include <hip/hip_runtime.h>

#define CD 768
#define NHEAD 12
#define DH 64
#define BSZ 2
#define NM_ 4096
#define NX_ 16384
#define EPSF 1e-6f
#define KSTR 1536   // ushort stride of in-place bf16 rows inside an fp32 buffer

using bf16x8 = __attribute__((ext_vector_type(8))) short;
using f32x4  = __attribute__((ext_vector_type(4))) float;

__device__ inline unsigned short bf16r(float f) {
  union { float f; unsigned u; } un; un.f = f;
  unsigned u = un.u;
  u += 0x7fffu + ((u >> 16) & 1u);
  return (unsigned short)(u >> 16);
}
__device__ inline float b2f(unsigned short u) {
  union { unsigned u; float f; } x; x.u = ((unsigned)u) << 16; return x.f;
}
// async global->LDS, 16B per lane; LDS dest = wave-uniform base + lane*16
__device__ inline void gl2lds16(const void* g, void* l) {
  __builtin_amdgcn_global_load_lds(
      (const __attribute__((address_space(1))) void*)g,
      (__attribute__((address_space(3))) void*)l, 16, 0, 0);
}

// ---------------- convert f32 -> bf16 (vectorized x4) ----------------
__global__ __launch_bounds__(256) void cvt_bf16(const float* __restrict__ in,
                                                unsigned short* __restrict__ out, int n4) {
  int i = blockIdx.x * 256 + threadIdx.x;
  if (i >= n4) return;
  float4 v = ((const float4*)in)[i];
  ushort4 o;
  o.x = bf16r(v.x); o.y = bf16r(v.y); o.z = bf16r(v.z); o.w = bf16r(v.w);
  ((ushort4*)out)[i] = o;
}

// ---------------- softplus(scale) -> sp[768] ----------------
__global__ void softplus_k(const float* __restrict__ s, float* __restrict__ sp) {
  int i = blockIdx.x * 256 + threadIdx.x;
  if (i < CD) sp[i] = log1pf(expf(s[i]));
}

// ------- 128x128-tile GEMM: C[M,N] = A[M,K] @ B[N,K]^T (+bias), bf16 in -----
// m97 structure: global_load_lds width-16 staging, 4 waves, 4x4 16x16 tiles/wave.
template<int OUTBF>
__global__ __launch_bounds__(256) void gemm128(const unsigned short* __restrict__ A,
                                               const unsigned short* __restrict__ B,
                                               void* __restrict__ Cv,
                                               const float* __restrict__ bias,
                                               int M, int N, int K) {
  __shared__ __align__(16) unsigned short As[128 * 32];
  __shared__ __align__(16) unsigned short Bs[128 * 32];
  const int m0 = blockIdx.x * 128, n0 = blockIdx.y * 128;
  const int tid = threadIdx.x, wave = tid >> 6, lane = tid & 63;
  const int quad = lane >> 4, l16 = lane & 15;
  const int wm = (wave >> 1) * 64, wn = (wave & 1) * 64;
  const int srow = lane >> 2, scol = (lane & 3) * 8;  // 16 rows/chunk, 4 lanes/row
  f32x4 acc[4][4] = {};
  for (int k0 = 0; k0 < K; k0 += 32) {
    __syncthreads();
    #pragma unroll
    for (int c2 = 0; c2 < 2; ++c2) {
      int ch = wave * 2 + c2;                 // 8 chunks of 16 rows each
      gl2lds16(A + (size_t)(m0 + ch * 16 + srow) * K + k0 + scol, (void*)(As + ch * 512));
      gl2lds16(B + (size_t)(n0 + ch * 16 + srow) * K + k0 + scol, (void*)(Bs + ch * 512));
    }
    __syncthreads();
    bf16x8 a[4], bb[4];
    #pragma unroll
    for (int t = 0; t < 4; ++t) {
      a[t]  = *(const bf16x8*)(As + (wm + t * 16 + l16) * 32 + quad * 8);
      bb[t] = *(const bf16x8*)(Bs + (wn + t * 16 + l16) * 32 + quad * 8);
    }
    #pragma unroll
    for (int tm = 0; tm < 4; ++tm)
      #pragma unroll
      for (int tn = 0; tn < 4; ++tn)
        acc[tm][tn] = __builtin_amdgcn_mfma_f32_16x16x32_bf16(a[tm], bb[tn], acc[tm][tn], 0, 0, 0);
  }
  // D layout: col = lane&15, row = quad*4 + r  [m89/m91 verified]
  #pragma unroll
  for (int tm = 0; tm < 4; ++tm)
    #pragma unroll
    for (int tn = 0; tn < 4; ++tn) {
      const int col = n0 + wn + tn * 16 + l16;
      const float bv = bias ? bias[col] : 0.f;
      #pragma unroll
      for (int r = 0; r < 4; ++r) {
        const int row = m0 + wm + tm * 16 + quad * 4 + r;
        float v = acc[tm][tn][r] + bv;
        if (OUTBF) ((unsigned short*)Cv)[(size_t)row * N + col] = bf16r(v);
        else       ((float*)Cv)[(size_t)row * N + col] = v;
      }
    }
}

// ------- _process: read fp32 row, write bf16 row IN-PLACE (stride KSTR) -------
__global__ __launch_bounds__(256) void process_rows(float* __restrict__ X,
                                                    const float* __restrict__ sp) {
  const int row = blockIdx.x;
  const int tid = threadIdx.x;
  float* xr = X + (size_t)row * CD;
  float tv[3];
  float n2 = 0.f, m2 = 0.f;
  #pragma unroll
  for (int i = 0; i < 3; ++i) {
    int c = tid + i * 256;
    float t = fmaxf(xr[c], 0.f) + EPSF;
    t = t / sp[c];
    tv[i] = t;
    float t2 = t * t;
    n2 += t2;
    float p = t2 * t;
    m2 += p * p;
  }
  #pragma unroll
  for (int off = 32; off; off >>= 1) {
    n2 += __shfl_down(n2, off, 64);
    m2 += __shfl_down(m2, off, 64);
  }
  __shared__ float rn[4], rm[4];
  if ((tid & 63) == 0) { rn[tid >> 6] = n2; rm[tid >> 6] = m2; }
  __syncthreads();   // also orders: all global reads done before bf16 overwrite
  float N2 = rn[0] + rn[1] + rn[2] + rn[3];
  float M2 = rm[0] + rm[1] + rm[2] + rm[3];
  float factor = sqrtf(N2 / M2);   // = ||t|| / ||t^3||
  unsigned short* xo = (unsigned short*)xr;
  #pragma unroll
  for (int i = 0; i < 3; ++i) {
    int c = tid + i * 256;
    float t = tv[i];
    xo[c] = bf16r(t * t * t * factor);
  }
}

// ------------- k_mean[b,c] = (1/Nm) sum_n k_bf16 (stride KSTR) -------------
__global__ __launch_bounds__(256) void kmean_k(const unsigned short* __restrict__ Kp,
                                               float* __restrict__ km) {
  int blk = blockIdx.x;            // B * 3 * 16 = 96 blocks
  int b = blk / 48;
  int r = blk % 48;
  int cch = r / 16, nch = r % 16;
  int c = cch * 256 + threadIdx.x;
  float s = 0.f;
  for (int i = 0; i < 256; ++i) {
    int n = nch * 256 + i;
    s += b2f(Kp[((size_t)n * BSZ + b) * KSTR + c]);
  }
  atomicAdd(&km[b * CD + c], s * (1.f / NM_));
}

// -------- kv[bh,d,e] = (1/Nm) sum_n k[n,d]*v[n,e], bf16 in, split-K atomic ---
__global__ __launch_bounds__(256) void kv_k(const unsigned short* __restrict__ Kp,
                                            const unsigned short* __restrict__ Vp,
                                            float* __restrict__ kv) {
  const int bh = blockIdx.x;
  const int b = bh / NHEAD, hh = bh % NHEAD;
  const int nch = blockIdx.y;          // 16 chunks of 256 tokens
  __shared__ float ks[64][68];
  __shared__ float vs[64][68];
  const int tid = threadIdx.x;
  const int d = tid & 63, eg = tid >> 6;
  const int rn = tid >> 2, cb = (tid & 3) * 16;
  float acc[16];
  #pragma unroll
  for (int j = 0; j < 16; ++j) acc[j] = 0.f;
  for (int sub = 0; sub < 4; ++sub) {
    int n0 = nch * 256 + sub * 64;
    __syncthreads();
    const unsigned short* kg = Kp + ((size_t)(n0 + rn) * BSZ + b) * KSTR + hh * 64 + cb;
    const unsigned short* vg = Vp + ((size_t)(n0 + rn) * BSZ + b) * CD + hh * 64 + cb;
    #pragma unroll
    for (int i = 0; i < 4; ++i) {
      ushort4 k4 = *(const ushort4*)(kg + i * 4);
      ushort4 v4 = *(const ushort4*)(vg + i * 4);
      ks[rn][cb + i * 4 + 0] = b2f(k4.x); ks[rn][cb + i * 4 + 1] = b2f(k4.y);
      ks[rn][cb + i * 4 + 2] = b2f(k4.z); ks[rn][cb + i * 4 + 3] = b2f(k4.w);
      vs[rn][cb + i * 4 + 0] = b2f(v4.x); vs[rn][cb + i * 4 + 1] = b2f(v4.y);
      vs[rn][cb + i * 4 + 2] = b2f(v4.z); vs[rn][cb + i * 4 + 3] = b2f(v4.w);
    }
    __syncthreads();
    for (int n = 0; n < 64; ++n) {
      float a = ks[n][d];
      const float* vr = &vs[n][eg * 16];
      #pragma unroll
      for (int j = 0; j < 16; ++j) acc[j] += a * vr[j];
    }
  }
  float* outp = kv + (size_t)bh * 4096 + d * 64 + eg * 16;
  #pragma unroll
  for (int j = 0; j < 16; ++j) atomicAdd(&outp[j], acc[j] * (1.f / NM_));
}

// ---- kvT[bh][e][d] = bf16(kv[bh][d][e]) : B-fragment-friendly layout -------
__global__ __launch_bounds__(256) void cvt_kvT(const float* __restrict__ kv,
                                               unsigned short* __restrict__ kvT) {
  int idx = blockIdx.x * 256 + threadIdx.x;   // 24*4096
  if (idx >= BSZ * NHEAD * 4096) return;
  int bh = idx >> 12, r = idx & 4095;
  int e = r >> 6, d = r & 63;
  kvT[(size_t)bh * 4096 + (size_t)e * 64 + d] = bf16r(kv[(size_t)bh * 4096 + (size_t)d * 64 + e]);
}

// ---------------- depthwise 5x5 conv, bf16 in/out ----------------
__global__ __launch_bounds__(256) void dwconv_k(const unsigned short* __restrict__ Vp,
                                                const float* __restrict__ w,
                                                const float* __restrict__ bias,
                                                unsigned short* __restrict__ outp) {
  __shared__ float wsm[64 * 25];
  __shared__ float bsm[64];
  for (int i = threadIdx.x; i < 1600; i += 256) wsm[i] = w[i];
  if (threadIdx.x < 64) bsm[threadIdx.x] = bias[threadIdx.x];
  __syncthreads();
  int idx = blockIdx.x * 256 + threadIdx.x;     // total NM_*BSZ*CD
  if (idx >= NM_ * BSZ * CD) return;
  int c = idx % CD;
  int b = (idx / CD) % BSZ;
  int m = idx / (CD * BSZ);
  int dd = c & 63;
  int y = m >> 8, x = m & 255;
  float s = bsm[dd];
  #pragma unroll
  for (int dy = 0; dy < 5; ++dy) {
    int yy = y + dy - 2;
    if (yy < 0 || yy >= 16) continue;
    #pragma unroll
    for (int dx = 0; dx < 5; ++dx) {
      int xx = x + dx - 2;
      if (xx < 0 || xx >= 256) continue;
      s += wsm[dd * 25 + dy * 5 + dx] *
           b2f(Vp[((size_t)((yy << 8) + xx) * BSZ + b) * CD + c]);
    }
  }
  outp[idx] = bf16r(s);   // layout (m*B + b)*C + c
}

// ------ attn: tmp = bf16( z * (q @ kv) + dwc ), MFMA per head, K=64 ---------
// block: one (b,h), 128 rows of n. q rows stride KSTR (in-place bf16).
__global__ __launch_bounds__(256) void attn_mfma(const unsigned short* __restrict__ Qb,
                                                 const unsigned short* __restrict__ kvT,
                                                 const float* __restrict__ km,
                                                 const unsigned short* __restrict__ dwcb,
                                                 unsigned short* __restrict__ tmpb) {
  __shared__ __align__(16) unsigned short qs[128 * 64];
  __shared__ __align__(16) unsigned short kvs[64 * 64];
  __shared__ float kms[64];
  __shared__ float zs[128];
  const int bh = blockIdx.x, b = bh / NHEAD, h = bh % NHEAD;
  const int n0 = blockIdx.y * 128;
  const int tid = threadIdx.x, wave = tid >> 6, lane = tid & 63;
  const int quad = lane >> 4, l16 = lane & 15;
  // stage q: 16 chunks of 8 rows (1KB); 8 lanes/row, 16B each
  #pragma unroll
  for (int c2 = 0; c2 < 4; ++c2) {
    int ch = wave * 4 + c2;
    int row = ch * 8 + (lane >> 3);
    int col = (lane & 7) * 8;
    gl2lds16(Qb + ((size_t)(n0 + row) * BSZ + b) * KSTR + h * 64 + col, (void*)(qs + ch * 512));
  }
  // stage kvT: 8 chunks of 8 rows(e)
  #pragma unroll
  for (int c2 = 0; c2 < 2; ++c2) {
    int ch = wave * 2 + c2;
    int e = ch * 8 + (lane >> 3);
    int col = (lane & 7) * 8;
    gl2lds16(kvT + (size_t)bh * 4096 + e * 64 + col, (void*)(kvs + ch * 512));
  }
  if (tid < 64) kms[tid] = km[b * CD + h * 64 + tid];
  __syncthreads();
  if (tid < 128) {
    float s = 0.f;
    for (int d2 = 0; d2 < 64; ++d2) s += b2f(qs[tid * 64 + d2]) * kms[d2];
    zs[tid] = 1.f / (s + EPSF);
  }
  __syncthreads();
  f32x4 acc[2][4] = {};
  #pragma unroll
  for (int kh = 0; kh < 2; ++kh) {
    bf16x8 a0 = *(const bf16x8*)(qs + (wave * 32 + l16) * 64 + kh * 32 + quad * 8);
    bf16x8 a1 = *(const bf16x8*)(qs + (wave * 32 + 16 + l16) * 64 + kh * 32 + quad * 8);
    bf16x8 bt[4];
    #pragma unroll
    for (int tn = 0; tn < 4; ++tn)
      bt[tn] = *(const bf16x8*)(kvs + (tn * 16 + l16) * 64 + kh * 32 + quad * 8);
    #pragma unroll
    for (int tn = 0; tn < 4; ++tn) {
      acc[0][tn] = __builtin_amdgcn_mfma_f32_16x16x32_bf16(a0, bt[tn], acc[0][tn], 0, 0, 0);
      acc[1][tn] = __builtin_amdgcn_mfma_f32_16x16x32_bf16(a1, bt[tn], acc[1][tn], 0, 0, 0);
    }
  }
  #pragma unroll
  for (int tm = 0; tm < 2; ++tm)
    #pragma unroll
    for (int tn = 0; tn < 4; ++tn)
      #pragma unroll
      for (int r = 0; r < 4; ++r) {
        int rl = wave * 32 + tm * 16 + quad * 4 + r;
        int n = n0 + rl;
        int m = n & (NM_ - 1);
        int c = h * 64 + tn * 16 + l16;
        float val = acc[tm][tn][r] * zs[rl] + b2f(dwcb[((size_t)m * BSZ + b) * CD + c]);
        tmpb[((size_t)n * BSZ + b) * CD + c] = bf16r(val);
      }
}

// =============================== launcher ===============================
extern "C" void kernel_launch(void* const* d_in, const int* in_sizes, int n_in,
                              void* d_out, int out_size, void* d_ws, size_t ws_size,
                              hipStream_t stream) {
  const float* x      = (const float*)d_in[0];
  const float* memory = (const float*)d_in[1];
  const float* w_q    = (const float*)d_in[2];
  const float* w_k    = (const float*)d_in[3];
  const float* w_v    = (const float*)d_in[4];
  const float* w_proj = (const float*)d_in[5];
  const float* b_proj = (const float*)d_in[6];
  const float* dwc_w  = (const float*)d_in[7];
  const float* dwc_b  = (const float*)d_in[8];
  const float* scale  = (const float*)d_in[9];
  float* out = (float*)d_out;

  const int Mq = NX_ * BSZ;   // 32768
  const int Mm = NM_ * BSZ;   // 8192

  char* ws = (char*)d_ws;
  size_t off = 0;
  auto alloc = [&](size_t bytes) -> void* {
    void* p = ws + off;
    off += (bytes + 255) & ~(size_t)255;
    return p;
  };
  float* q    = (float*)alloc((size_t)Mq * CD * 4);   // fp32, later bf16 in-place (stride KSTR)
  float* kbuf = (float*)alloc((size_t)Mm * CD * 4);   // fp32, later bf16 in-place
  float* kv   = (float*)alloc((size_t)BSZ * NHEAD * DH * DH * 4);
  float* km   = (float*)alloc((size_t)BSZ * CD * 4);
  float* sp   = (float*)alloc(CD * 4);
  unsigned short* xb   = (unsigned short*)alloc((size_t)Mq * CD * 2);  // reused as tmpb
  unsigned short* mb   = (unsigned short*)alloc((size_t)Mm * CD * 2);
  unsigned short* vb   = (unsigned short*)alloc((size_t)Mm * CD * 2);  // bf16 v
  unsigned short* dwcb = (unsigned short*)alloc((size_t)Mm * CD * 2);
  unsigned short* kvT  = (unsigned short*)alloc((size_t)BSZ * NHEAD * DH * DH * 2);
  unsigned short* wqb  = (unsigned short*)alloc((size_t)CD * CD * 2);
  unsigned short* wkb  = (unsigned short*)alloc((size_t)CD * CD * 2);
  unsigned short* wvb  = (unsigned short*)alloc((size_t)CD * CD * 2);
  unsigned short* wpb  = (unsigned short*)alloc((size_t)CD * CD * 2);

  hipMemsetAsync(kv, 0, (size_t)BSZ * NHEAD * DH * DH * 4, stream);
  hipMemsetAsync(km, 0, (size_t)BSZ * CD * 4, stream);

  softplus_k<<<3, 256, 0, stream>>>(scale, sp);

  auto cvt = [&](const float* src, unsigned short* dst, size_t n) {
    int n4 = (int)(n / 4);
    cvt_bf16<<<(n4 + 255) / 256, 256, 0, stream>>>(src, dst, n4);
  };
  cvt(x,      xb,  (size_t)Mq * CD);
  cvt(memory, mb,  (size_t)Mm * CD);
  cvt(w_q,    wqb, (size_t)CD * CD);
  cvt(w_k,    wkb, (size_t)CD * CD);
  cvt(w_v,    wvb, (size_t)CD * CD);
  cvt(w_proj, wpb, (size_t)CD * CD);

  gemm128<0><<<dim3(Mq / 128, CD / 128), 256, 0, stream>>>(xb, wqb, q,    nullptr, Mq, CD, CD);
  gemm128<0><<<dim3(Mm / 128, CD / 128), 256, 0, stream>>>(mb, wkb, kbuf, nullptr, Mm, CD, CD);
  gemm128<1><<<dim3(Mm / 128, CD / 128), 256, 0, stream>>>(mb, wvb, vb,   nullptr, Mm, CD, CD);

  process_rows<<<Mq, 256, 0, stream>>>(q, sp);     // q -> bf16 in-place
  process_rows<<<Mm, 256, 0, stream>>>(kbuf, sp);  // k -> bf16 in-place

  const unsigned short* qb = (const unsigned short*)q;
  const unsigned short* kb = (const unsigned short*)kbuf;

  kmean_k<<<96, 256, 0, stream>>>(kb, km);
  kv_k<<<dim3(BSZ * NHEAD, 16), 256, 0, stream>>>(kb, vb, kv);
  cvt_kvT<<<(BSZ * NHEAD * 4096 + 255) / 256, 256, 0, stream>>>(kv, kvT);

  dwconv_k<<<(NM_ * BSZ * CD) / 256, 256, 0, stream>>>(vb, dwc_w, dwc_b, dwcb);

  unsigned short* tmpb = xb;  // xb fully consumed by q GEMM; reuse
  attn_mfma<<<dim3(BSZ * NHEAD, NX_ / 128), 256, 0, stream>>>(qb, kvT, km, dwcb, tmpb);

  gemm128<0><<<dim3(Mq / 128, CD / 128), 256, 0, stream>>>(tmpb, wpb, out, b_proj, Mq, CD, CD);
}

// Round 3
// 606.564 us; speedup vs baseline: 1.3978x; 1.1328x over previous
//
#include <hip/hip_runtime.h>

#define CD 768
#define NHEAD 12
#define DH 64
#define BSZ 2
#define NM_ 4096
#define NX_ 16384
#define EPSF 1e-6f
#define KSTR 1536   // ushort stride of in-place bf16 rows inside an fp32 buffer

using bf16x8 = __attribute__((ext_vector_type(8))) short;
using f32x4  = __attribute__((ext_vector_type(4))) float;

__device__ inline unsigned short bf16r(float f) {
  union { float f; unsigned u; } un; un.f = f;
  unsigned u = un.u;
  u += 0x7fffu + ((u >> 16) & 1u);
  return (unsigned short)(u >> 16);
}
__device__ inline float b2f(unsigned short u) {
  union { unsigned u; float f; } x; x.u = ((unsigned)u) << 16; return x.f;
}
__device__ inline float asf(unsigned u) {
  union { unsigned u; float f; } x; x.u = u; return x.f;
}
// async global->LDS, 16B per lane; LDS dest = wave-uniform base + lane*16
__device__ inline void gl2lds16(const void* g, void* l) {
  __builtin_amdgcn_global_load_lds(
      (const __attribute__((address_space(1))) void*)g,
      (__attribute__((address_space(3))) void*)l, 16, 0, 0);
}

// ---------------- convert f32 -> bf16 (vectorized x4) ----------------
__global__ __launch_bounds__(256) void cvt_bf16(const float* __restrict__ in,
                                                unsigned short* __restrict__ out, int n4) {
  int i = blockIdx.x * 256 + threadIdx.x;
  if (i >= n4) return;
  float4 v = ((const float4*)in)[i];
  ushort4 o;
  o.x = bf16r(v.x); o.y = bf16r(v.y); o.z = bf16r(v.z); o.w = bf16r(v.w);
  ((ushort4*)out)[i] = o;
}

// ---------------- softplus(scale) -> sp[768] ----------------
__global__ void softplus_k(const float* __restrict__ s, float* __restrict__ sp) {
  int i = blockIdx.x * 256 + threadIdx.x;
  if (i < CD) sp[i] = log1pf(expf(s[i]));
}

// ------- 128x128-tile GEMM: C[M,N] = A[M,K] @ B[N,K]^T (+bias), bf16 in -----
template<int OUTBF>
__global__ __launch_bounds__(256) void gemm128(const unsigned short* __restrict__ A,
                                               const unsigned short* __restrict__ B,
                                               void* __restrict__ Cv,
                                               const float* __restrict__ bias,
                                               int M, int N, int K) {
  __shared__ __align__(16) unsigned short As[128 * 32];
  __shared__ __align__(16) unsigned short Bs[128 * 32];
  const int m0 = blockIdx.x * 128, n0 = blockIdx.y * 128;
  const int tid = threadIdx.x, wave = tid >> 6, lane = tid & 63;
  const int quad = lane >> 4, l16 = lane & 15;
  const int wm = (wave >> 1) * 64, wn = (wave & 1) * 64;
  const int srow = lane >> 2, scol = (lane & 3) * 8;  // 16 rows/chunk, 4 lanes/row
  f32x4 acc[4][4] = {};
  for (int k0 = 0; k0 < K; k0 += 32) {
    __syncthreads();
    #pragma unroll
    for (int c2 = 0; c2 < 2; ++c2) {
      int ch = wave * 2 + c2;                 // 8 chunks of 16 rows each
      gl2lds16(A + (size_t)(m0 + ch * 16 + srow) * K + k0 + scol, (void*)(As + ch * 512));
      gl2lds16(B + (size_t)(n0 + ch * 16 + srow) * K + k0 + scol, (void*)(Bs + ch * 512));
    }
    __syncthreads();
    bf16x8 a[4], bb[4];
    #pragma unroll
    for (int t = 0; t < 4; ++t) {
      a[t]  = *(const bf16x8*)(As + (wm + t * 16 + l16) * 32 + quad * 8);
      bb[t] = *(const bf16x8*)(Bs + (wn + t * 16 + l16) * 32 + quad * 8);
    }
    #pragma unroll
    for (int tm = 0; tm < 4; ++tm)
      #pragma unroll
      for (int tn = 0; tn < 4; ++tn)
        acc[tm][tn] = __builtin_amdgcn_mfma_f32_16x16x32_bf16(a[tm], bb[tn], acc[tm][tn], 0, 0, 0);
  }
  // D layout: col = lane&15, row = quad*4 + r  [m89/m91 verified]
  #pragma unroll
  for (int tm = 0; tm < 4; ++tm)
    #pragma unroll
    for (int tn = 0; tn < 4; ++tn) {
      const int col = n0 + wn + tn * 16 + l16;
      const float bv = bias ? bias[col] : 0.f;
      #pragma unroll
      for (int r = 0; r < 4; ++r) {
        const int row = m0 + wm + tm * 16 + quad * 4 + r;
        float v = acc[tm][tn][r] + bv;
        if (OUTBF) ((unsigned short*)Cv)[(size_t)row * N + col] = bf16r(v);
        else       ((float*)Cv)[(size_t)row * N + col] = v;
      }
    }
}

// ------- _process: read fp32 row, write bf16 row IN-PLACE (stride KSTR) -------
__global__ __launch_bounds__(256) void process_rows(float* __restrict__ X,
                                                    const float* __restrict__ sp) {
  const int row = blockIdx.x;
  const int tid = threadIdx.x;
  float* xr = X + (size_t)row * CD;
  float tv[3];
  float n2 = 0.f, m2 = 0.f;
  #pragma unroll
  for (int i = 0; i < 3; ++i) {
    int c = tid + i * 256;
    float t = fmaxf(xr[c], 0.f) + EPSF;
    t = t / sp[c];
    tv[i] = t;
    float t2 = t * t;
    n2 += t2;
    float p = t2 * t;
    m2 += p * p;
  }
  #pragma unroll
  for (int off = 32; off; off >>= 1) {
    n2 += __shfl_down(n2, off, 64);
    m2 += __shfl_down(m2, off, 64);
  }
  __shared__ float rn[4], rm[4];
  if ((tid & 63) == 0) { rn[tid >> 6] = n2; rm[tid >> 6] = m2; }
  __syncthreads();   // also orders: all global reads done before bf16 overwrite
  float N2 = rn[0] + rn[1] + rn[2] + rn[3];
  float M2 = rm[0] + rm[1] + rm[2] + rm[3];
  float factor = sqrtf(N2 / M2);   // = ||t|| / ||t^3||
  unsigned short* xo = (unsigned short*)xr;
  #pragma unroll
  for (int i = 0; i < 3; ++i) {
    int c = tid + i * 256;
    float t = tv[i];
    xo[c] = bf16r(t * t * t * factor);
  }
}

// ------------- k_mean[b,c] = (1/Nm) sum_n k_bf16 (stride KSTR) -------------
__global__ __launch_bounds__(256) void kmean_k(const unsigned short* __restrict__ Kp,
                                               float* __restrict__ km) {
  int blk = blockIdx.x;            // B * 3 * 16 = 96 blocks
  int b = blk / 48;
  int r = blk % 48;
  int cch = r / 16, nch = r % 16;
  int c = cch * 256 + threadIdx.x;
  float s = 0.f;
  for (int i = 0; i < 256; ++i) {
    int n = nch * 256 + i;
    s += b2f(Kp[((size_t)n * BSZ + b) * KSTR + c]);
  }
  atomicAdd(&km[b * CD + c], s * (1.f / NM_));
}

// -------- kv[bh,d,e] = (1/Nm) sum_n k[n,d]*v[n,e], bf16 in, split-K atomic ---
__global__ __launch_bounds__(256) void kv_k(const unsigned short* __restrict__ Kp,
                                            const unsigned short* __restrict__ Vp,
                                            float* __restrict__ kv) {
  const int bh = blockIdx.x;
  const int b = bh / NHEAD, hh = bh % NHEAD;
  const int nch = blockIdx.y;          // 16 chunks of 256 tokens
  __shared__ float ks[64][68];
  __shared__ float vs[64][68];
  const int tid = threadIdx.x;
  const int d = tid & 63, eg = tid >> 6;
  const int rn = tid >> 2, cb = (tid & 3) * 16;
  float acc[16];
  #pragma unroll
  for (int j = 0; j < 16; ++j) acc[j] = 0.f;
  for (int sub = 0; sub < 4; ++sub) {
    int n0 = nch * 256 + sub * 64;
    __syncthreads();
    const unsigned short* kg = Kp + ((size_t)(n0 + rn) * BSZ + b) * KSTR + hh * 64 + cb;
    const unsigned short* vg = Vp + ((size_t)(n0 + rn) * BSZ + b) * CD + hh * 64 + cb;
    #pragma unroll
    for (int i = 0; i < 4; ++i) {
      ushort4 k4 = *(const ushort4*)(kg + i * 4);
      ushort4 v4 = *(const ushort4*)(vg + i * 4);
      ks[rn][cb + i * 4 + 0] = b2f(k4.x); ks[rn][cb + i * 4 + 1] = b2f(k4.y);
      ks[rn][cb + i * 4 + 2] = b2f(k4.z); ks[rn][cb + i * 4 + 3] = b2f(k4.w);
      vs[rn][cb + i * 4 + 0] = b2f(v4.x); vs[rn][cb + i * 4 + 1] = b2f(v4.y);
      vs[rn][cb + i * 4 + 2] = b2f(v4.z); vs[rn][cb + i * 4 + 3] = b2f(v4.w);
    }
    __syncthreads();
    for (int n = 0; n < 64; ++n) {
      float a = ks[n][d];
      const float* vr = &vs[n][eg * 16];
      #pragma unroll
      for (int j = 0; j < 16; ++j) acc[j] += a * vr[j];
    }
  }
  float* outp = kv + (size_t)bh * 4096 + d * 64 + eg * 16;
  #pragma unroll
  for (int j = 0; j < 16; ++j) atomicAdd(&outp[j], acc[j] * (1.f / NM_));
}

// ---- kvT[bh][e][d] = bf16(kv[bh][d][e]) : B-fragment-friendly layout -------
__global__ __launch_bounds__(256) void cvt_kvT(const float* __restrict__ kv,
                                               unsigned short* __restrict__ kvT) {
  int idx = blockIdx.x * 256 + threadIdx.x;   // 24*4096
  if (idx >= BSZ * NHEAD * 4096) return;
  int bh = idx >> 12, r = idx & 4095;
  int e = r >> 6, d = r & 63;
  kvT[(size_t)bh * 4096 + (size_t)e * 64 + d] = bf16r(kv[(size_t)bh * 4096 + (size_t)d * 64 + e]);
}

// -------- depthwise 5x5 conv, LDS-tiled: block = (b,h) x 16-wide x-tile ------
// v layout: ((y*256+x)*B + b)*C + h*64 + dd, bf16. Stage (16y, 20x, 64ch) tile.
__global__ __launch_bounds__(256) void dwconv_k(const unsigned short* __restrict__ Vp,
                                                const float* __restrict__ w,
                                                const float* __restrict__ bias,
                                                unsigned short* __restrict__ outp) {
  __shared__ __align__(16) unsigned ls32[16 * 20 * 32];  // ushort2-packed channels
  __shared__ float wsm[64 * 25];
  __shared__ float bsm[64];
  const int tid = threadIdx.x;
  const int bh = blockIdx.x, b = bh / NHEAD, h = bh % NHEAD;
  const int x0 = blockIdx.y * 16;
  for (int i = tid; i < 1600; i += 256) wsm[i] = w[i];
  if (tid < 64) bsm[tid] = bias[tid];
  // stage: 320 (y,xp) pairs, 128B (64ch) each; 8 lanes/pair, 16B/lane
  const int lch = (tid & 7) * 8;
  #pragma unroll
  for (int it = 0; it < 10; ++it) {
    int p = it * 32 + (tid >> 3);
    int y = p / 20, xp = p % 20;
    int xx = x0 + xp - 2;
    int4 val = {0, 0, 0, 0};
    if (xx >= 0 && xx < 256)
      val = *(const int4*)(Vp + ((size_t)((y << 8) + xx) * BSZ + b) * CD + h * 64 + lch);
    *(int4*)((unsigned short*)ls32 + p * 64 + lch) = val;
  }
  __syncthreads();
  const int cp = tid & 31;        // channel pair: ch = {2cp, 2cp+1}
  const int xs = tid >> 5;        // 0..7 -> x outputs {2xs, 2xs+1}
  float wr0[25], wr1[25];
  #pragma unroll
  for (int t = 0; t < 25; ++t) { wr0[t] = wsm[(cp * 2) * 25 + t]; wr1[t] = wsm[(cp * 2 + 1) * 25 + t]; }
  const float b0 = bsm[cp * 2], b1 = bsm[cp * 2 + 1];
  for (int y = 0; y < 16; ++y) {
    float a00 = b0, a01 = b1, a10 = b0, a11 = b1;   // (x0+2xs, ch0/1), (x0+2xs+1, ch0/1)
    #pragma unroll
    for (int dy = 0; dy < 5; ++dy) {
      int yy = y + dy - 2;
      if (yy < 0 || yy >= 16) continue;
      #pragma unroll
      for (int dx = 0; dx < 5; ++dx) {
        int base = (yy * 20 + xs * 2 + dx) * 32 + cp;
        unsigned u0 = ls32[base], u1 = ls32[base + 32];
        float w0 = wr0[dy * 5 + dx], w1 = wr1[dy * 5 + dx];
        a00 += w0 * asf(u0 << 16);  a01 += w1 * asf(u0 & 0xffff0000u);
        a10 += w0 * asf(u1 << 16);  a11 += w1 * asf(u1 & 0xffff0000u);
      }
    }
    const int x = x0 + xs * 2;
    size_t o = ((size_t)((y << 8) + x) * BSZ + b) * CD + h * 64 + cp * 2;
    ushort2 s0; s0.x = bf16r(a00); s0.y = bf16r(a01);
    ushort2 s1; s1.x = bf16r(a10); s1.y = bf16r(a11);
    *(ushort2*)(outp + o) = s0;
    *(ushort2*)(outp + o + (size_t)BSZ * CD) = s1;
  }
}

// ------ attn: tmp = bf16( z * (q @ kv) + dwc ), MFMA per head, K=64 ---------
__global__ __launch_bounds__(256) void attn_mfma(const unsigned short* __restrict__ Qb,
                                                 const unsigned short* __restrict__ kvT,
                                                 const float* __restrict__ km,
                                                 const unsigned short* __restrict__ dwcb,
                                                 unsigned short* __restrict__ tmpb) {
  __shared__ __align__(16) unsigned short qs[128 * 64];
  __shared__ __align__(16) unsigned short kvs[64 * 64];
  __shared__ float kms[64];
  __shared__ float zs[128];
  const int bh = blockIdx.x, b = bh / NHEAD, h = bh % NHEAD;
  const int n0 = blockIdx.y * 128;
  const int tid = threadIdx.x, wave = tid >> 6, lane = tid & 63;
  const int quad = lane >> 4, l16 = lane & 15;
  #pragma unroll
  for (int c2 = 0; c2 < 4; ++c2) {
    int ch = wave * 4 + c2;
    int row = ch * 8 + (lane >> 3);
    int col = (lane & 7) * 8;
    gl2lds16(Qb + ((size_t)(n0 + row) * BSZ + b) * KSTR + h * 64 + col, (void*)(qs + ch * 512));
  }
  #pragma unroll
  for (int c2 = 0; c2 < 2; ++c2) {
    int ch = wave * 2 + c2;
    int e = ch * 8 + (lane >> 3);
    int col = (lane & 7) * 8;
    gl2lds16(kvT + (size_t)bh * 4096 + e * 64 + col, (void*)(kvs + ch * 512));
  }
  if (tid < 64) kms[tid] = km[b * CD + h * 64 + tid];
  __syncthreads();
  if (tid < 128) {
    float s = 0.f;
    for (int d2 = 0; d2 < 64; ++d2) s += b2f(qs[tid * 64 + d2]) * kms[d2];
    zs[tid] = 1.f / (s + EPSF);
  }
  __syncthreads();
  f32x4 acc[2][4] = {};
  #pragma unroll
  for (int kh = 0; kh < 2; ++kh) {
    bf16x8 a0 = *(const bf16x8*)(qs + (wave * 32 + l16) * 64 + kh * 32 + quad * 8);
    bf16x8 a1 = *(const bf16x8*)(qs + (wave * 32 + 16 + l16) * 64 + kh * 32 + quad * 8);
    bf16x8 bt[4];
    #pragma unroll
    for (int tn = 0; tn < 4; ++tn)
      bt[tn] = *(const bf16x8*)(kvs + (tn * 16 + l16) * 64 + kh * 32 + quad * 8);
    #pragma unroll
    for (int tn = 0; tn < 4; ++tn) {
      acc[0][tn] = __builtin_amdgcn_mfma_f32_16x16x32_bf16(a0, bt[tn], acc[0][tn], 0, 0, 0);
      acc[1][tn] = __builtin_amdgcn_mfma_f32_16x16x32_bf16(a1, bt[tn], acc[1][tn], 0, 0, 0);
    }
  }
  #pragma unroll
  for (int tm = 0; tm < 2; ++tm)
    #pragma unroll
    for (int tn = 0; tn < 4; ++tn)
      #pragma unroll
      for (int r = 0; r < 4; ++r) {
        int rl = wave * 32 + tm * 16 + quad * 4 + r;
        int n = n0 + rl;
        int m = n & (NM_ - 1);
        int c = h * 64 + tn * 16 + l16;
        float val = acc[tm][tn][r] * zs[rl] + b2f(dwcb[((size_t)m * BSZ + b) * CD + c]);
        tmpb[((size_t)n * BSZ + b) * CD + c] = bf16r(val);
      }
}

// =============================== launcher ===============================
extern "C" void kernel_launch(void* const* d_in, const int* in_sizes, int n_in,
                              void* d_out, int out_size, void* d_ws, size_t ws_size,
                              hipStream_t stream) {
  const float* x      = (const float*)d_in[0];
  const float* memory = (const float*)d_in[1];
  const float* w_q    = (const float*)d_in[2];
  const float* w_k    = (const float*)d_in[3];
  const float* w_v    = (const float*)d_in[4];
  const float* w_proj = (const float*)d_in[5];
  const float* b_proj = (const float*)d_in[6];
  const float* dwc_w  = (const float*)d_in[7];
  const float* dwc_b  = (const float*)d_in[8];
  const float* scale  = (const float*)d_in[9];
  float* out = (float*)d_out;

  const int Mq = NX_ * BSZ;   // 32768
  const int Mm = NM_ * BSZ;   // 8192

  char* ws = (char*)d_ws;
  size_t off = 0;
  auto alloc = [&](size_t bytes) -> void* {
    void* p = ws + off;
    off += (bytes + 255) & ~(size_t)255;
    return p;
  };
  float* q    = (float*)alloc((size_t)Mq * CD * 4);   // fp32, later bf16 in-place (stride KSTR)
  float* kbuf = (float*)alloc((size_t)Mm * CD * 4);   // fp32, later bf16 in-place
  float* kv   = (float*)alloc((size_t)BSZ * NHEAD * DH * DH * 4);
  float* km   = (float*)alloc((size_t)BSZ * CD * 4);
  float* sp   = (float*)alloc(CD * 4);
  unsigned short* xb   = (unsigned short*)alloc((size_t)Mq * CD * 2);  // reused as tmpb
  unsigned short* mb   = (unsigned short*)alloc((size_t)Mm * CD * 2);
  unsigned short* vb   = (unsigned short*)alloc((size_t)Mm * CD * 2);  // bf16 v
  unsigned short* dwcb = (unsigned short*)alloc((size_t)Mm * CD * 2);
  unsigned short* kvT  = (unsigned short*)alloc((size_t)BSZ * NHEAD * DH * DH * 2);
  unsigned short* wqb  = (unsigned short*)alloc((size_t)CD * CD * 2);
  unsigned short* wkb  = (unsigned short*)alloc((size_t)CD * CD * 2);
  unsigned short* wvb  = (unsigned short*)alloc((size_t)CD * CD * 2);
  unsigned short* wpb  = (unsigned short*)alloc((size_t)CD * CD * 2);

  hipMemsetAsync(kv, 0, (size_t)BSZ * NHEAD * DH * DH * 4, stream);
  hipMemsetAsync(km, 0, (size_t)BSZ * CD * 4, stream);

  softplus_k<<<3, 256, 0, stream>>>(scale, sp);

  auto cvt = [&](const float* src, unsigned short* dst, size_t n) {
    int n4 = (int)(n / 4);
    cvt_bf16<<<(n4 + 255) / 256, 256, 0, stream>>>(src, dst, n4);
  };
  cvt(x,      xb,  (size_t)Mq * CD);
  cvt(memory, mb,  (size_t)Mm * CD);
  cvt(w_q,    wqb, (size_t)CD * CD);
  cvt(w_k,    wkb, (size_t)CD * CD);
  cvt(w_v,    wvb, (size_t)CD * CD);
  cvt(w_proj, wpb, (size_t)CD * CD);

  gemm128<0><<<dim3(Mq / 128, CD / 128), 256, 0, stream>>>(xb, wqb, q,    nullptr, Mq, CD, CD);
  gemm128<0><<<dim3(Mm / 128, CD / 128), 256, 0, stream>>>(mb, wkb, kbuf, nullptr, Mm, CD, CD);
  gemm128<1><<<dim3(Mm / 128, CD / 128), 256, 0, stream>>>(mb, wvb, vb,   nullptr, Mm, CD, CD);

  process_rows<<<Mq, 256, 0, stream>>>(q, sp);     // q -> bf16 in-place
  process_rows<<<Mm, 256, 0, stream>>>(kbuf, sp);  // k -> bf16 in-place

  const unsigned short* qb = (const unsigned short*)q;
  const unsigned short* kb = (const unsigned short*)kbuf;

  kmean_k<<<96, 256, 0, stream>>>(kb, km);
  kv_k<<<dim3(BSZ * NHEAD, 16), 256, 0, stream>>>(kb, vb, kv);
  cvt_kvT<<<(BSZ * NHEAD * 4096 + 255) / 256, 256, 0, stream>>>(kv, kvT);

  dwconv_k<<<dim3(BSZ * NHEAD, 16), 256, 0, stream>>>(vb, dwc_w, dwc_b, dwcb);

  unsigned short* tmpb = xb;  // xb fully consumed by q GEMM; reuse
  attn_mfma<<<dim3(BSZ * NHEAD, NX_ / 128), 256, 0, stream>>>(qb, kvT, km, dwcb, tmpb);

  gemm128<0><<<dim3(Mq / 128, CD / 128), 256, 0, stream>>>(tmpb, wpb, out, b_proj, Mq, CD, CD);
}

// Round 4
// 517.825 us; speedup vs baseline: 1.6373x; 1.1714x over previous
//
#include <hip/hip_runtime.h>

#define CD 768
#define NHEAD 12
#define DH 64
#define BSZ 2
#define NM_ 4096
#define NX_ 16384
#define EPSF 1e-6f
#define KSTR 1536   // ushort stride of in-place bf16 rows inside an fp32 buffer
#define KVCH 32     // split-K chunks for kv partials

using bf16x8 = __attribute__((ext_vector_type(8))) short;
using f32x4  = __attribute__((ext_vector_type(4))) float;

__device__ inline unsigned short bf16r(float f) {
  union { float f; unsigned u; } un; un.f = f;
  unsigned u = un.u;
  u += 0x7fffu + ((u >> 16) & 1u);
  return (unsigned short)(u >> 16);
}
__device__ inline float b2f(unsigned short u) {
  union { unsigned u; float f; } x; x.u = ((unsigned)u) << 16; return x.f;
}
__device__ inline float asf(unsigned u) {
  union { unsigned u; float f; } x; x.u = u; return x.f;
}
// async global->LDS, 16B per lane; LDS dest = wave-uniform base + lane*16
__device__ inline void gl2lds16(const void* g, void* l) {
  __builtin_amdgcn_global_load_lds(
      (const __attribute__((address_space(1))) void*)g,
      (__attribute__((address_space(3))) void*)l, 16, 0, 0);
}

// ---- prep: 4 weight matrices fp32->bf16 + softplus(scale), ONE dispatch ----
__global__ __launch_bounds__(256) void prep_k(const float* __restrict__ w0, const float* __restrict__ w1,
                                              const float* __restrict__ w2, const float* __restrict__ w3,
                                              const float* __restrict__ scale,
                                              unsigned short* __restrict__ o0, unsigned short* __restrict__ o1,
                                              unsigned short* __restrict__ o2, unsigned short* __restrict__ o3,
                                              float* __restrict__ sp) {
  int bx = blockIdx.x;
  if (bx < 2304) {                    // 4 matrices x 576 blocks x 256 float4
    int m = bx / 576;
    int i = (bx % 576) * 256 + threadIdx.x;
    const float* w = m == 0 ? w0 : m == 1 ? w1 : m == 2 ? w2 : w3;
    unsigned short* o = m == 0 ? o0 : m == 1 ? o1 : m == 2 ? o2 : o3;
    float4 v = ((const float4*)w)[i];
    ushort4 u; u.x = bf16r(v.x); u.y = bf16r(v.y); u.z = bf16r(v.z); u.w = bf16r(v.w);
    ((ushort4*)o)[i] = u;
  } else {
    int i = (bx - 2304) * 256 + threadIdx.x;
    if (i < CD) sp[i] = log1pf(expf(scale[i]));
  }
}

// ------- 128x128-tile GEMM: C[M,N] = A[M,K] @ B[N,K]^T (+bias) --------------
// AFP32: A is fp32, converted to bf16 during LDS staging (conflict-free map).
template<int AFP32, int OUTBF>
__global__ __launch_bounds__(256) void gemm128(const void* __restrict__ Av,
                                               const unsigned short* __restrict__ B,
                                               void* __restrict__ Cv,
                                               const float* __restrict__ bias,
                                               int M, int N, int K) {
  __shared__ __align__(16) unsigned short As[128 * 32];
  __shared__ __align__(16) unsigned short Bs[128 * 32];
  const int m0 = blockIdx.x * 128, n0 = blockIdx.y * 128;
  const int tid = threadIdx.x, wave = tid >> 6, lane = tid & 63;
  const int quad = lane >> 4, l16 = lane & 15;
  const int wm = (wave >> 1) * 64, wn = (wave & 1) * 64;
  const int srow = lane >> 2, scol = (lane & 3) * 8;  // gl2lds: 16 rows/chunk, 4 lanes/row
  const int ar = tid >> 2, ac = (tid & 3) * 8;        // fp32-A staging map
  f32x4 acc[4][4] = {};
  for (int k0 = 0; k0 < K; k0 += 32) {
    float4 f0, f1, f2, f3;
    if (AFP32) {
      const float* Af = (const float*)Av;
      f0 = *(const float4*)(Af + (size_t)(m0 + ar) * K + k0 + ac);
      f1 = *(const float4*)(Af + (size_t)(m0 + ar) * K + k0 + ac + 4);
      f2 = *(const float4*)(Af + (size_t)(m0 + ar + 64) * K + k0 + ac);
      f3 = *(const float4*)(Af + (size_t)(m0 + ar + 64) * K + k0 + ac + 4);
    }
    __syncthreads();
    if (AFP32) {
      ushort4 u0, u1, u2, u3;
      u0.x = bf16r(f0.x); u0.y = bf16r(f0.y); u0.z = bf16r(f0.z); u0.w = bf16r(f0.w);
      u1.x = bf16r(f1.x); u1.y = bf16r(f1.y); u1.z = bf16r(f1.z); u1.w = bf16r(f1.w);
      u2.x = bf16r(f2.x); u2.y = bf16r(f2.y); u2.z = bf16r(f2.z); u2.w = bf16r(f2.w);
      u3.x = bf16r(f3.x); u3.y = bf16r(f3.y); u3.z = bf16r(f3.z); u3.w = bf16r(f3.w);
      *(ushort4*)(As + ar * 32 + ac) = u0;
      *(ushort4*)(As + ar * 32 + ac + 4) = u1;
      *(ushort4*)(As + (ar + 64) * 32 + ac) = u2;
      *(ushort4*)(As + (ar + 64) * 32 + ac + 4) = u3;
    } else {
      const unsigned short* A = (const unsigned short*)Av;
      #pragma unroll
      for (int c2 = 0; c2 < 2; ++c2) {
        int ch = wave * 2 + c2;
        gl2lds16(A + (size_t)(m0 + ch * 16 + srow) * K + k0 + scol, (void*)(As + ch * 512));
      }
    }
    #pragma unroll
    for (int c2 = 0; c2 < 2; ++c2) {
      int ch = wave * 2 + c2;
      gl2lds16(B + (size_t)(n0 + ch * 16 + srow) * K + k0 + scol, (void*)(Bs + ch * 512));
    }
    __syncthreads();
    bf16x8 a[4], bb[4];
    #pragma unroll
    for (int t = 0; t < 4; ++t) {
      a[t]  = *(const bf16x8*)(As + (wm + t * 16 + l16) * 32 + quad * 8);
      bb[t] = *(const bf16x8*)(Bs + (wn + t * 16 + l16) * 32 + quad * 8);
    }
    #pragma unroll
    for (int tm = 0; tm < 4; ++tm)
      #pragma unroll
      for (int tn = 0; tn < 4; ++tn)
        acc[tm][tn] = __builtin_amdgcn_mfma_f32_16x16x32_bf16(a[tm], bb[tn], acc[tm][tn], 0, 0, 0);
  }
  // D layout: col = lane&15, row = quad*4 + r  [m89/m91 verified]
  #pragma unroll
  for (int tm = 0; tm < 4; ++tm)
    #pragma unroll
    for (int tn = 0; tn < 4; ++tn) {
      const int col = n0 + wn + tn * 16 + l16;
      const float bv = bias ? bias[col] : 0.f;
      #pragma unroll
      for (int r = 0; r < 4; ++r) {
        const int row = m0 + wm + tm * 16 + quad * 4 + r;
        float v = acc[tm][tn][r] + bv;
        if (OUTBF) ((unsigned short*)Cv)[(size_t)row * N + col] = bf16r(v);
        else       ((float*)Cv)[(size_t)row * N + col] = v;
      }
    }
}

// ------- _process: read fp32 row, write bf16 row IN-PLACE (stride KSTR) -------
__global__ __launch_bounds__(256) void process_rows(float* __restrict__ X,
                                                    const float* __restrict__ sp) {
  const int row = blockIdx.x;
  const int tid = threadIdx.x;
  float* xr = X + (size_t)row * CD;
  float tv[3];
  float n2 = 0.f, m2 = 0.f;
  #pragma unroll
  for (int i = 0; i < 3; ++i) {
    int c = tid + i * 256;
    float t = fmaxf(xr[c], 0.f) + EPSF;
    t = t / sp[c];
    tv[i] = t;
    float t2 = t * t;
    n2 += t2;
    float p = t2 * t;
    m2 += p * p;
  }
  #pragma unroll
  for (int off = 32; off; off >>= 1) {
    n2 += __shfl_down(n2, off, 64);
    m2 += __shfl_down(m2, off, 64);
  }
  __shared__ float rn[4], rm[4];
  if ((tid & 63) == 0) { rn[tid >> 6] = n2; rm[tid >> 6] = m2; }
  __syncthreads();   // also orders: all global reads done before bf16 overwrite
  float N2 = rn[0] + rn[1] + rn[2] + rn[3];
  float M2 = rm[0] + rm[1] + rm[2] + rm[3];
  float factor = sqrtf(N2 / M2);   // = ||t|| / ||t^3||
  unsigned short* xo = (unsigned short*)xr;
  #pragma unroll
  for (int i = 0; i < 3; ++i) {
    int c = tid + i * 256;
    float t = tv[i];
    xo[c] = bf16r(t * t * t * factor);
  }
}

// ---- kv partials: kvp[ch][bh][d][e] = sum_{n in chunk} k[n,d]*v[n,e] --------
// also kmp[ch][bh][d] = sum_{n in chunk} k[n,d]. No atomics.
__global__ __launch_bounds__(256) void kv_part_k(const unsigned short* __restrict__ Kp,
                                                 const unsigned short* __restrict__ Vp,
                                                 float* __restrict__ kvp,
                                                 float* __restrict__ kmp) {
  const int bh = blockIdx.x, chunk = blockIdx.y;
  const int b = bh / NHEAD, h = bh % NHEAD;
  const int n0 = chunk * 128;
  __shared__ __align__(16) unsigned short ks[128 * 72];
  __shared__ __align__(16) unsigned short vs[128 * 72];
  const int tid = threadIdx.x;
  #pragma unroll
  for (int it = 0; it < 4; ++it) {
    int g = it * 256 + tid;            // 1024 groups of 8 elements per tile
    int row = g >> 3, c8 = (g & 7) * 8;
    int4 ka = *(const int4*)(Kp + ((size_t)(n0 + row) * BSZ + b) * KSTR + h * 64 + c8);
    int4 va = *(const int4*)(Vp + ((size_t)(n0 + row) * BSZ + b) * CD + h * 64 + c8);
    *(int4*)(ks + row * 72 + c8) = ka;
    *(int4*)(vs + row * 72 + c8) = va;
  }
  __syncthreads();
  const int d0 = (tid >> 4) * 4, e0 = (tid & 15) * 4;
  float acc[4][4] = {};
  #pragma unroll 4
  for (int n = 0; n < 128; ++n) {
    ushort4 kd = *(const ushort4*)(ks + n * 72 + d0);
    ushort4 ve = *(const ushort4*)(vs + n * 72 + e0);
    float kf[4] = {b2f(kd.x), b2f(kd.y), b2f(kd.z), b2f(kd.w)};
    float vf[4] = {b2f(ve.x), b2f(ve.y), b2f(ve.z), b2f(ve.w)};
    #pragma unroll
    for (int i = 0; i < 4; ++i)
      #pragma unroll
      for (int j = 0; j < 4; ++j) acc[i][j] += kf[i] * vf[j];
  }
  float* outp = kvp + ((size_t)chunk * 24 + bh) * 4096;
  #pragma unroll
  for (int i = 0; i < 4; ++i) {
    float4 o; o.x = acc[i][0]; o.y = acc[i][1]; o.z = acc[i][2]; o.w = acc[i][3];
    *(float4*)(outp + (d0 + i) * 64 + e0) = o;
  }
  if (tid < 64) {
    float s = 0.f;
    for (int n = 0; n < 128; ++n) s += b2f(ks[n * 72 + tid]);
    kmp[((size_t)chunk * 24 + bh) * 64 + tid] = s;
  }
}

// ---- reduce partials -> kvT[bh][e][d] bf16 (+1/Nm) and km[b][c] fp32 --------
__global__ __launch_bounds__(256) void kv_reduce_k(const float* __restrict__ kvp,
                                                   const float* __restrict__ kmp,
                                                   unsigned short* __restrict__ kvT,
                                                   float* __restrict__ km) {
  const int tid = threadIdx.x;
  const int bx = blockIdx.x;
  if (bx < 24) {
    __shared__ float t[64 * 65];
    float acc[16] = {};
    const float* base = kvp + (size_t)bx * 4096 + tid * 16;
    for (int c = 0; c < KVCH; ++c) {
      const float* p = base + (size_t)c * 24 * 4096;
      #pragma unroll
      for (int i = 0; i < 4; ++i) {
        float4 v = *(const float4*)(p + i * 4);
        acc[i * 4 + 0] += v.x; acc[i * 4 + 1] += v.y; acc[i * 4 + 2] += v.z; acc[i * 4 + 3] += v.w;
      }
    }
    const int d = tid >> 2, e0 = (tid & 3) * 16;   // writes row d, cols e0..e0+15
    #pragma unroll
    for (int i = 0; i < 16; ++i) t[d * 65 + e0 + i] = acc[i] * (1.f / NM_);
    __syncthreads();
    const int e = tid >> 2, dd0 = (tid & 3) * 16;  // read col e, rows dd0..+15
    ushort4 o[4];
    #pragma unroll
    for (int i = 0; i < 16; ++i)
      ((unsigned short*)o)[i] = bf16r(t[(dd0 + i) * 65 + e]);
    unsigned short* dst = kvT + (size_t)bx * 4096 + e * 64 + dd0;
    *(ushort4*)(dst) = o[0]; *(ushort4*)(dst + 4) = o[1];
    *(ushort4*)(dst + 8) = o[2]; *(ushort4*)(dst + 12) = o[3];
  } else {
    int i = (bx - 24) * 256 + tid;                 // 6 blocks cover 1536 outputs
    if (i < 24 * 64) {
      int bhh = i >> 6, d = i & 63;
      float s = 0.f;
      for (int c = 0; c < KVCH; ++c) s += kmp[((size_t)c * 24 + bhh) * 64 + d];
      int b = bhh / NHEAD, h = bhh % NHEAD;
      km[b * CD + h * 64 + d] = s * (1.f / NM_);
    }
  }
}

// -------- depthwise 5x5 conv, LDS-tiled: block = (b,h) x 16-wide x-tile ------
__global__ __launch_bounds__(256) void dwconv_k(const unsigned short* __restrict__ Vp,
                                                const float* __restrict__ w,
                                                const float* __restrict__ bias,
                                                unsigned short* __restrict__ outp) {
  __shared__ __align__(16) unsigned ls32[16 * 20 * 32];  // ushort2-packed channels
  __shared__ float wsm[64 * 25];
  __shared__ float bsm[64];
  const int tid = threadIdx.x;
  const int bh = blockIdx.x, b = bh / NHEAD, h = bh % NHEAD;
  const int x0 = blockIdx.y * 16;
  for (int i = tid; i < 1600; i += 256) wsm[i] = w[i];
  if (tid < 64) bsm[tid] = bias[tid];
  const int lch = (tid & 7) * 8;
  #pragma unroll
  for (int it = 0; it < 10; ++it) {
    int p = it * 32 + (tid >> 3);
    int y = p / 20, xp = p % 20;
    int xx = x0 + xp - 2;
    int4 val = {0, 0, 0, 0};
    if (xx >= 0 && xx < 256)
      val = *(const int4*)(Vp + ((size_t)((y << 8) + xx) * BSZ + b) * CD + h * 64 + lch);
    *(int4*)((unsigned short*)ls32 + p * 64 + lch) = val;
  }
  __syncthreads();
  const int cp = tid & 31;        // channel pair: ch = {2cp, 2cp+1}
  const int xs = tid >> 5;        // 0..7 -> x outputs {2xs, 2xs+1}
  float wr0[25], wr1[25];
  #pragma unroll
  for (int t = 0; t < 25; ++t) { wr0[t] = wsm[(cp * 2) * 25 + t]; wr1[t] = wsm[(cp * 2 + 1) * 25 + t]; }
  const float b0 = bsm[cp * 2], b1 = bsm[cp * 2 + 1];
  for (int y = 0; y < 16; ++y) {
    float a00 = b0, a01 = b1, a10 = b0, a11 = b1;
    #pragma unroll
    for (int dy = 0; dy < 5; ++dy) {
      int yy = y + dy - 2;
      if (yy < 0 || yy >= 16) continue;
      #pragma unroll
      for (int dx = 0; dx < 5; ++dx) {
        int base = (yy * 20 + xs * 2 + dx) * 32 + cp;
        unsigned u0 = ls32[base], u1 = ls32[base + 32];
        float w0 = wr0[dy * 5 + dx], w1 = wr1[dy * 5 + dx];
        a00 += w0 * asf(u0 << 16);  a01 += w1 * asf(u0 & 0xffff0000u);
        a10 += w0 * asf(u1 << 16);  a11 += w1 * asf(u1 & 0xffff0000u);
      }
    }
    const int x = x0 + xs * 2;
    size_t o = ((size_t)((y << 8) + x) * BSZ + b) * CD + h * 64 + cp * 2;
    ushort2 s0; s0.x = bf16r(a00); s0.y = bf16r(a01);
    ushort2 s1; s1.x = bf16r(a10); s1.y = bf16r(a11);
    *(ushort2*)(outp + o) = s0;
    *(ushort2*)(outp + o + (size_t)BSZ * CD) = s1;
  }
}

// ------ attn: tmp = bf16( z * (q @ kv) + dwc ), MFMA per head, K=64 ---------
__global__ __launch_bounds__(256) void attn_mfma(const unsigned short* __restrict__ Qb,
                                                 const unsigned short* __restrict__ kvT,
                                                 const float* __restrict__ km,
                                                 const unsigned short* __restrict__ dwcb,
                                                 unsigned short* __restrict__ tmpb) {
  __shared__ __align__(16) unsigned short qs[128 * 64];
  __shared__ __align__(16) unsigned short kvs[64 * 64];
  __shared__ float kms[64];
  __shared__ float zs[128];
  const int bh = blockIdx.x, b = bh / NHEAD, h = bh % NHEAD;
  const int n0 = blockIdx.y * 128;
  const int tid = threadIdx.x, wave = tid >> 6, lane = tid & 63;
  const int quad = lane >> 4, l16 = lane & 15;
  #pragma unroll
  for (int c2 = 0; c2 < 4; ++c2) {
    int ch = wave * 4 + c2;
    int row = ch * 8 + (lane >> 3);
    int col = (lane & 7) * 8;
    gl2lds16(Qb + ((size_t)(n0 + row) * BSZ + b) * KSTR + h * 64 + col, (void*)(qs + ch * 512));
  }
  #pragma unroll
  for (int c2 = 0; c2 < 2; ++c2) {
    int ch = wave * 2 + c2;
    int e = ch * 8 + (lane >> 3);
    int col = (lane & 7) * 8;
    gl2lds16(kvT + (size_t)bh * 4096 + e * 64 + col, (void*)(kvs + ch * 512));
  }
  if (tid < 64) kms[tid] = km[b * CD + h * 64 + tid];
  __syncthreads();
  if (tid < 128) {
    float s = 0.f;
    for (int d2 = 0; d2 < 64; ++d2) s += b2f(qs[tid * 64 + d2]) * kms[d2];
    zs[tid] = 1.f / (s + EPSF);
  }
  __syncthreads();
  f32x4 acc[2][4] = {};
  #pragma unroll
  for (int kh = 0; kh < 2; ++kh) {
    bf16x8 a0 = *(const bf16x8*)(qs + (wave * 32 + l16) * 64 + kh * 32 + quad * 8);
    bf16x8 a1 = *(const bf16x8*)(qs + (wave * 32 + 16 + l16) * 64 + kh * 32 + quad * 8);
    bf16x8 bt[4];
    #pragma unroll
    for (int tn = 0; tn < 4; ++tn)
      bt[tn] = *(const bf16x8*)(kvs + (tn * 16 + l16) * 64 + kh * 32 + quad * 8);
    #pragma unroll
    for (int tn = 0; tn < 4; ++tn) {
      acc[0][tn] = __builtin_amdgcn_mfma_f32_16x16x32_bf16(a0, bt[tn], acc[0][tn], 0, 0, 0);
      acc[1][tn] = __builtin_amdgcn_mfma_f32_16x16x32_bf16(a1, bt[tn], acc[1][tn], 0, 0, 0);
    }
  }
  #pragma unroll
  for (int tm = 0; tm < 2; ++tm)
    #pragma unroll
    for (int tn = 0; tn < 4; ++tn)
      #pragma unroll
      for (int r = 0; r < 4; ++r) {
        int rl = wave * 32 + tm * 16 + quad * 4 + r;
        int n = n0 + rl;
        int m = n & (NM_ - 1);
        int c = h * 64 + tn * 16 + l16;
        float val = acc[tm][tn][r] * zs[rl] + b2f(dwcb[((size_t)m * BSZ + b) * CD + c]);
        tmpb[((size_t)n * BSZ + b) * CD + c] = bf16r(val);
      }
}

// =============================== launcher ===============================
extern "C" void kernel_launch(void* const* d_in, const int* in_sizes, int n_in,
                              void* d_out, int out_size, void* d_ws, size_t ws_size,
                              hipStream_t stream) {
  const float* x      = (const float*)d_in[0];
  const float* memory = (const float*)d_in[1];
  const float* w_q    = (const float*)d_in[2];
  const float* w_k    = (const float*)d_in[3];
  const float* w_v    = (const float*)d_in[4];
  const float* w_proj = (const float*)d_in[5];
  const float* b_proj = (const float*)d_in[6];
  const float* dwc_w  = (const float*)d_in[7];
  const float* dwc_b  = (const float*)d_in[8];
  const float* scale  = (const float*)d_in[9];
  float* out = (float*)d_out;

  const int Mq = NX_ * BSZ;   // 32768
  const int Mm = NM_ * BSZ;   // 8192

  char* ws = (char*)d_ws;
  size_t off = 0;
  auto alloc = [&](size_t bytes) -> void* {
    void* p = ws + off;
    off += (bytes + 255) & ~(size_t)255;
    return p;
  };
  float* q    = (float*)alloc((size_t)Mq * CD * 4);   // fp32, later bf16 in-place (stride KSTR)
  float* kbuf = (float*)alloc((size_t)Mm * CD * 4);   // fp32, later bf16 in-place
  float* kvp  = (float*)alloc((size_t)KVCH * 24 * 4096 * 4);   // 12.6 MB partials
  float* kmp  = (float*)alloc((size_t)KVCH * 24 * 64 * 4);
  float* km   = (float*)alloc((size_t)BSZ * CD * 4);
  float* sp   = (float*)alloc(CD * 4);
  unsigned short* tmpb = (unsigned short*)alloc((size_t)Mq * CD * 2);
  unsigned short* vb   = (unsigned short*)alloc((size_t)Mm * CD * 2);  // bf16 v
  unsigned short* dwcb = (unsigned short*)alloc((size_t)Mm * CD * 2);
  unsigned short* kvT  = (unsigned short*)alloc((size_t)BSZ * NHEAD * DH * DH * 2);
  unsigned short* wqb  = (unsigned short*)alloc((size_t)CD * CD * 2);
  unsigned short* wkb  = (unsigned short*)alloc((size_t)CD * CD * 2);
  unsigned short* wvb  = (unsigned short*)alloc((size_t)CD * CD * 2);
  unsigned short* wpb  = (unsigned short*)alloc((size_t)CD * CD * 2);

  prep_k<<<2307, 256, 0, stream>>>(w_q, w_k, w_v, w_proj, scale, wqb, wkb, wvb, wpb, sp);

  gemm128<1, 0><<<dim3(Mq / 128, CD / 128), 256, 0, stream>>>(x,      wqb, q,    nullptr, Mq, CD, CD);
  gemm128<1, 0><<<dim3(Mm / 128, CD / 128), 256, 0, stream>>>(memory, wkb, kbuf, nullptr, Mm, CD, CD);
  gemm128<1, 1><<<dim3(Mm / 128, CD / 128), 256, 0, stream>>>(memory, wvb, vb,   nullptr, Mm, CD, CD);

  process_rows<<<Mq, 256, 0, stream>>>(q, sp);     // q -> bf16 in-place
  process_rows<<<Mm, 256, 0, stream>>>(kbuf, sp);  // k -> bf16 in-place

  const unsigned short* qb = (const unsigned short*)q;
  const unsigned short* kb = (const unsigned short*)kbuf;

  kv_part_k<<<dim3(24, KVCH), 256, 0, stream>>>(kb, vb, kvp, kmp);
  kv_reduce_k<<<30, 256, 0, stream>>>(kvp, kmp, kvT, km);

  dwconv_k<<<dim3(BSZ * NHEAD, 16), 256, 0, stream>>>(vb, dwc_w, dwc_b, dwcb);

  attn_mfma<<<dim3(BSZ * NHEAD, NX_ / 128), 256, 0, stream>>>(qb, kvT, km, dwcb, tmpb);

  gemm128<0, 0><<<dim3(Mq / 128, CD / 128), 256, 0, stream>>>(tmpb, wpb, out, b_proj, Mq, CD, CD);
}